// Round 1
// baseline (309.854 us; speedup 1.0000x reference)
//
#include <hip/hip_runtime.h>
#include <stdint.h>

// Fused 2x tiny-LSTM (H=1) over T=512, B=4096, F=25 (12+13 split) + sigmoid head.
// v2: occupancy + pipeline-depth rework.
//  - 2048 blocks x 64 threads (1 wave/block, CH=2 chains/block) -> 8 blocks/CU,
//    i.e. 2 waves on EVERY SIMD (was 2 waves/CU on 2 of 4 SIMDs).
//  - split-gate GEMV: each lane computes ONE LSTM's 4 gates for one timestep;
//    LSTM1 weights zero-padded to 13 wide so both halves run identical code.
//  - triple-buffered x staging, counted s_waitcnt vmcnt(4): 2 tiles per wave
//    stay in flight continuously (was vmcnt(0) full drain, 1 bursty tile).

#define T_STEPS 512
#define F_IN    25
#define TC      16
#define NTILES  (T_STEPS / TC)     // 32
#define CH      2                  // chains (batch elems) per block
#define XROW    520                // padded floats per chain per x tile (400 data + pad)
#define ZROW    136                // 16 timesteps * 8 gates + 8 pad
#define XBUF    (CH * XROW)        // 1040 floats per x buffer
#define ZBUF    (CH * ZROW)        // 272 floats per z buffer
#define LOG2E   1.44269504088896340736f

typedef const __attribute__((address_space(1))) void* as1_cvp;
typedef __attribute__((address_space(3)))       void* as3_vp;

__device__ __forceinline__ void gll16(const float* gsrc, const float* ldst) {
  // async global->LDS, 16 B/lane. LDS dst is wave-uniform base + lane*16.
  __builtin_amdgcn_global_load_lds((as1_cvp)(uintptr_t)gsrc,
                                   (as3_vp)(uint32_t)(uintptr_t)ldst, 16, 0, 0);
}

__device__ __forceinline__ float sigm(float v) {
  return __builtin_amdgcn_rcpf(1.0f + __builtin_amdgcn_exp2f(v * (-LOG2E)));
}
__device__ __forceinline__ float tanh_(float v) {
  // tanh(x) = 2*sigmoid(2x) - 1
  return fmaf(2.0f, __builtin_amdgcn_rcpf(1.0f + __builtin_amdgcn_exp2f(v * (-2.0f * LOG2E))), -1.0f);
}

__device__ __forceinline__ void prefetch_tile(const float* __restrict__ x, int b0, int tile,
                                              float* xbuf, int lane) {
  // per chain: 400 contiguous floats (16 timesteps x 25) -> 2 GLL dwordx4 insts
  const float* base = x + (size_t)b0 * (T_STEPS * F_IN) + tile * (TC * F_IN);
  const int i1 = lane * 4;          // floats 0..255
  int i2 = 256 + lane * 4;          // floats 256..399 (+clamped lanes, harmless dup)
  if (i2 > 396) i2 = 396;
#pragma unroll
  for (int cc = 0; cc < CH; ++cc) {
    const float* g0 = base + cc * (T_STEPS * F_IN);
    gll16(g0 + i1, xbuf + cc * XROW);          // uniform LDS base per inst
    gll16(g0 + i2, xbuf + cc * XROW + 256);
  }
}

__device__ __forceinline__ void gemv_tile(const float* __restrict__ xbuf, float* __restrict__ zbuf,
                                          int c, int lt, int xoff, int zoff,
                                          const float* __restrict__ w, const float* __restrict__ zb) {
  // lane (c, half, lt): z[4] = W_ih(half) . x[t=lt] + b(half), 13-wide padded weights
  const float* xr = xbuf + c * XROW + lt * F_IN + xoff;
  float z0 = zb[0], z1 = zb[1], z2 = zb[2], z3 = zb[3];
#pragma unroll
  for (int f = 0; f < 13; ++f) {
    const float xv = xr[f];
    z0 = fmaf(w[0 * 13 + f], xv, z0);
    z1 = fmaf(w[1 * 13 + f], xv, z1);
    z2 = fmaf(w[2 * 13 + f], xv, z2);
    z3 = fmaf(w[3 * 13 + f], xv, z3);
  }
  *(float4*)(zbuf + c * ZROW + lt * 8 + zoff) = make_float4(z0, z1, z2, z3);
}

__device__ __forceinline__ void scan_tile(const float* __restrict__ zbuf, int c, int zoff,
                                          const float* __restrict__ whh, float& hv, float& cv) {
  // every lane of the (chain, half) group redundantly runs its LSTM recurrence
#pragma unroll
  for (int t = 0; t < TC; ++t) {
    const float4 z4 = *(const float4*)(zbuf + c * ZROW + t * 8 + zoff);
    const float pi = fmaf(hv, whh[0], z4.x);
    const float pf = fmaf(hv, whh[1], z4.y);
    const float pg = fmaf(hv, whh[2], z4.z);
    const float po = fmaf(hv, whh[3], z4.w);
    const float ai = sigm(pi);
    const float af = sigm(pf);
    const float ag = tanh_(pg);
    const float ao = sigm(po);
    cv = fmaf(af, cv, ai * ag);
    hv = ao * tanh_(cv);
  }
}

__global__ void __launch_bounds__(64, 2)
lstm2_fused(const float* __restrict__ x,
            const float* __restrict__ Wih1, const float* __restrict__ Whh1, const float* __restrict__ b1,
            const float* __restrict__ Wih2, const float* __restrict__ Whh2, const float* __restrict__ b2,
            const float* __restrict__ Wout, const float* __restrict__ bout,
            float* __restrict__ out)
{
  __shared__ __align__(16) float xs[3 * XBUF];   // 12480 B: triple-buffered x tiles
  __shared__ __align__(16) float zs[2 * ZBUF];   //  2176 B: double-buffered gate preacts

  const int lane = threadIdx.x;        // 0..63
  const int c    = lane >> 5;          // chain 0..1
  const int lt   = lane & 15;          // timestep within tile
  const int half = (lane >> 4) & 1;    // 0 -> LSTM1, 1 -> LSTM2
  const int xoff = half * 12;          // LSTM1 reads x[0..12] (w[12]=0), LSTM2 x[12..24]
  const int zoff = half * 4;
  const int b0   = blockIdx.x * CH;

  // per-lane weights for its LSTM, padded to 13 inputs (no divergence: cndmask select)
  float w[52], zb[4], whh[4];
#pragma unroll
  for (int j = 0; j < 4; ++j) {
#pragma unroll
    for (int f = 0; f < 13; ++f) {
      const float wa = (f < 12) ? Wih1[j * 12 + f] : 0.0f;
      const float wb = Wih2[j * 13 + f];
      w[j * 13 + f] = half ? wb : wa;
    }
    zb[j]  = half ? b2[j]   : b1[j];
    whh[j] = half ? Whh2[j] : Whh1[j];
  }

  float hv = 0.0f, cv = 0.0f;

  // ---- pipeline prologue: 3 tiles issued, 2 stay in flight from here on ----
  prefetch_tile(x, b0, 0, xs + 0 * XBUF, lane);
  prefetch_tile(x, b0, 1, xs + 1 * XBUF, lane);
  prefetch_tile(x, b0, 2, xs + 2 * XBUF, lane);
  asm volatile("s_waitcnt vmcnt(8)" ::: "memory");   // tile 0 staged; 1,2 in flight
  gemv_tile(xs, zs, c, lt, xoff, zoff, w, zb);
  asm volatile("s_waitcnt lgkmcnt(0)" ::: "memory"); // z-tile 0 visible

  // ---- steady state: scan(k) | GEMV(k+1) | prefetch(k+3), 2 tiles in flight ----
  int pb = 0;        // buffer receiving tile k+3  ((k+3)%3 == k%3)
  int rb = 1;        // buffer holding tile k+1    ((k+1)%3)
  for (int k = 0; k < NTILES - 1; ++k) {
    asm volatile("s_waitcnt vmcnt(4)" ::: "memory"); // tile k+1 staged, k+2 still in flight
    int tn = k + 3;
    if (tn > NTILES - 1) tn = NTILES - 1;            // tail: duplicate loads, L2-hot, unread
    prefetch_tile(x, b0, tn, xs + pb * XBUF, lane);
    pb = (pb == 2) ? 0 : pb + 1;
    const float* zrd = zs + (k & 1) * ZBUF;
    float*       zwr = zs + ((k + 1) & 1) * ZBUF;
    const float* xrd = xs + rb * XBUF;
    rb = (rb == 2) ? 0 : rb + 1;
    scan_tile(zrd, c, zoff, whh, hv, cv);            // latency-bound
    gemv_tile(xrd, zwr, c, lt, xoff, zoff, w, zb);   // throughput-bound, fills stalls
    asm volatile("s_waitcnt lgkmcnt(0)" ::: "memory");
  }
  scan_tile(zs + ZBUF, c, zoff, whh, hv, cv);        // tile 31 ((31&1)==1)
  asm volatile("s_waitcnt vmcnt(0)" ::: "memory");   // drain tail DMA before LDS dealloc

  // ---- head: out = sigmoid(W_out . [h1,h2] + b_out) ----
  const float h1 = __shfl(hv, (lane & 32) + 0, 64);
  const float h2 = __shfl(hv, (lane & 32) + 16, 64);
  if ((lane & 31) == 0) {
    out[b0 + c] = sigm(fmaf(Wout[0], h1, fmaf(Wout[1], h2, bout[0])));
  }
}

extern "C" void kernel_launch(void* const* d_in, const int* in_sizes, int n_in,
                              void* d_out, int out_size, void* d_ws, size_t ws_size,
                              hipStream_t stream) {
  const float* x    = (const float*)d_in[0];
  const float* Wih1 = (const float*)d_in[1];
  const float* Whh1 = (const float*)d_in[2];
  const float* b1   = (const float*)d_in[3];
  const float* Wih2 = (const float*)d_in[4];
  const float* Whh2 = (const float*)d_in[5];
  const float* b2   = (const float*)d_in[6];
  const float* Wout = (const float*)d_in[7];
  const float* bout = (const float*)d_in[8];
  float* out = (float*)d_out;

  const int B = in_sizes[0] / (T_STEPS * F_IN);      // 4096
  dim3 grid(B / CH), block(64);
  hipLaunchKernelGGL(lstm2_fused, grid, block, 0, stream,
                     x, Wih1, Whh1, b1, Wih2, Whh2, b2, Wout, bout, out);
}

// Round 2
// 307.134 us; speedup vs baseline: 1.0089x; 1.0089x over previous
//
#include <hip/hip_runtime.h>
#include <stdint.h>

// Fused 2x tiny-LSTM (H=1) over T=512, B=4096, F=25 (12+13 split) + sigmoid head.
// v3: scan-amortization rework. Insight: the serial-scan's issue cost
// (10 transcendentals + ~19 VALU per step) is paid PER WAVE regardless of how
// many lanes redundantly compute it. v2 served 2 chains per 30us of scan issue.
// v3 decouples the GEMV lane-mapping (fully packed, 4 chains x 2 halves x 8 t)
// from the scan lane-mapping (8 distinct recurrences = 4 chains x 2 LSTMs,
// 8-fold redundancy) -> 2x chains amortized per wave, and CH=4 -> 1024 blocks
// -> 1 wave on EVERY SIMD (4 blocks/CU), memory streaming over the full chip.

#define T_STEPS 512
#define F_IN    25
#define TC      16
#define NTILES  (T_STEPS / TC)     // 32
#define CH      4                  // chains (batch elems) per block
#define XROW    520                // floats per chain per x tile (400 data + 112 clamp-spill + pad)
#define ZROW    136                // 16 timesteps * 8 gates + 8 pad
#define XBUF    (CH * XROW)        // 2080 floats per x buffer
#define ZBUF    (CH * ZROW)        // 544 floats per z buffer
#define LOG2E   1.44269504088896340736f

typedef const __attribute__((address_space(1))) void* as1_cvp;
typedef __attribute__((address_space(3)))       void* as3_vp;

__device__ __forceinline__ void gll16(const float* gsrc, const float* ldst) {
  // async global->LDS, 16 B/lane. LDS dst is wave-uniform base + lane*16.
  __builtin_amdgcn_global_load_lds((as1_cvp)(uintptr_t)gsrc,
                                   (as3_vp)(uint32_t)(uintptr_t)ldst, 16, 0, 0);
}

__device__ __forceinline__ float sigm(float v) {
  return __builtin_amdgcn_rcpf(1.0f + __builtin_amdgcn_exp2f(v * (-LOG2E)));
}
__device__ __forceinline__ float tanh_(float v) {
  // tanh(x) = 2*sigmoid(2x) - 1
  return fmaf(2.0f, __builtin_amdgcn_rcpf(1.0f + __builtin_amdgcn_exp2f(v * (-2.0f * LOG2E))), -1.0f);
}

__device__ __forceinline__ void prefetch_tile(const float* __restrict__ x, int b0, int tile,
                                              float* xbuf, int lane) {
  // per chain: 400 contiguous floats (16 timesteps x 25) -> 2 GLL dwordx4 insts
  const float* base = x + (size_t)b0 * (T_STEPS * F_IN) + tile * (TC * F_IN);
  const int i1 = lane * 4;          // floats 0..255
  int i2 = 256 + lane * 4;          // floats 256..399 (clamped lanes spill into XROW pad)
  if (i2 > 396) i2 = 396;
#pragma unroll
  for (int cc = 0; cc < CH; ++cc) {
    const float* g0 = base + cc * (T_STEPS * F_IN);
    gll16(g0 + i1, xbuf + cc * XROW);          // uniform LDS base per inst
    gll16(g0 + i2, xbuf + cc * XROW + 256);    // writes LDS floats 256..511 (<520 ok)
  }
}

__device__ __forceinline__ void gemv_tile(const float* __restrict__ xbuf, float* __restrict__ zbuf,
                                          int cg, int lt, int xoff, int zoff,
                                          const float* __restrict__ w, const float* __restrict__ zb) {
  // packed mapping: lane (cg, half, lt) handles timesteps lt and lt+8:
  // z[4] = W_ih(half) . x[t] + b(half); LSTM1 weights zero-padded to 13 wide.
#pragma unroll
  for (int p = 0; p < 2; ++p) {
    const int tl = p * 8 + lt;
    const float* xr = xbuf + cg * XROW + tl * F_IN + xoff;
    float z0 = zb[0], z1 = zb[1], z2 = zb[2], z3 = zb[3];
#pragma unroll
    for (int f = 0; f < 13; ++f) {
      const float xv = xr[f];
      z0 = fmaf(w[0 * 13 + f], xv, z0);
      z1 = fmaf(w[1 * 13 + f], xv, z1);
      z2 = fmaf(w[2 * 13 + f], xv, z2);
      z3 = fmaf(w[3 * 13 + f], xv, z3);
    }
    *(float4*)(zbuf + cg * ZROW + tl * 8 + zoff) = make_float4(z0, z1, z2, z3);
  }
}

__device__ __forceinline__ void scan_tile(const float* __restrict__ zbuf, int cs, int zoff,
                                          const float* __restrict__ whh, float& hv, float& cv) {
  // scan mapping: 8 distinct recurrences (cs, half) over 8-lane groups.
  // Issue cost is per-wave; serving 8 recurrences halves v2's per-chain cost.
#pragma unroll
  for (int t = 0; t < TC; ++t) {
    const float4 z4 = *(const float4*)(zbuf + cs * ZROW + t * 8 + zoff);
    const float pi = fmaf(hv, whh[0], z4.x);
    const float pf = fmaf(hv, whh[1], z4.y);
    const float pg = fmaf(hv, whh[2], z4.z);
    const float po = fmaf(hv, whh[3], z4.w);
    const float ai = sigm(pi);
    const float af = sigm(pf);
    const float ag = tanh_(pg);
    const float ao = sigm(po);
    cv = fmaf(af, cv, ai * ag);
    hv = ao * tanh_(cv);
  }
}

__global__ void __launch_bounds__(64, 1)
lstm2_fused(const float* __restrict__ x,
            const float* __restrict__ Wih1, const float* __restrict__ Whh1, const float* __restrict__ b1,
            const float* __restrict__ Wih2, const float* __restrict__ Whh2, const float* __restrict__ b2,
            const float* __restrict__ Wout, const float* __restrict__ bout,
            float* __restrict__ out)
{
  __shared__ __align__(16) float xs[3 * XBUF];   // 24960 B: triple-buffered x tiles
  __shared__ __align__(16) float zs[2 * ZBUF];   //  4352 B: double-buffered gate preacts

  const int lane = threadIdx.x;        // 0..63
  // GEMV mapping: fully packed, no redundancy
  const int cg   = lane >> 4;          // chain 0..3
  const int hg   = (lane >> 3) & 1;    // 0 -> LSTM1, 1 -> LSTM2
  const int lt   = lane & 7;           // timestep slot (handles lt and lt+8)
  const int xoff = hg * 12;            // LSTM1 reads x[0..12] (w[12]=0), LSTM2 x[12..24]
  const int zofg = hg * 4;
  // scan mapping: 8 distinct recurrences, 8-fold redundancy
  const int cs   = lane & 3;           // chain 0..3
  const int hs   = (lane >> 2) & 1;    // 0 -> LSTM1, 1 -> LSTM2
  const int zofs = hs * 4;
  const int b0   = blockIdx.x * CH;

  // per-lane weights: GEMV set selected by hg, scan set by hs (cndmask, no divergence)
  float w[52], zb[4], whh[4];
#pragma unroll
  for (int j = 0; j < 4; ++j) {
#pragma unroll
    for (int f = 0; f < 13; ++f) {
      const float wa = (f < 12) ? Wih1[j * 12 + f] : 0.0f;
      const float wb = Wih2[j * 13 + f];
      w[j * 13 + f] = hg ? wb : wa;
    }
    zb[j]  = hg ? b2[j]   : b1[j];
    whh[j] = hs ? Whh2[j] : Whh1[j];
  }

  float hv = 0.0f, cv = 0.0f;

  // ---- pipeline prologue: 3 tiles issued (8 gll16 each), 2 stay in flight ----
  prefetch_tile(x, b0, 0, xs + 0 * XBUF, lane);
  prefetch_tile(x, b0, 1, xs + 1 * XBUF, lane);
  prefetch_tile(x, b0, 2, xs + 2 * XBUF, lane);
  asm volatile("s_waitcnt vmcnt(16)" ::: "memory");  // tile 0 staged; 1,2 in flight
  gemv_tile(xs, zs, cg, lt, xoff, zofg, w, zb);
  asm volatile("s_waitcnt lgkmcnt(0)" ::: "memory"); // z-tile 0 visible

  // ---- steady state: scan(k) | GEMV(k+1) | prefetch(k+3), 2 tiles in flight ----
  int pb = 0;        // buffer receiving tile k+3  ((k+3)%3 == k%3)
  int rb = 1;        // buffer holding tile k+1    ((k+1)%3)
  for (int k = 0; k < NTILES - 1; ++k) {
    asm volatile("s_waitcnt vmcnt(8)" ::: "memory"); // tile k+1 staged, k+2 in flight
    int tn = k + 3;
    if (tn > NTILES - 1) tn = NTILES - 1;            // tail: dup loads into dead buffer
    prefetch_tile(x, b0, tn, xs + pb * XBUF, lane);
    pb = (pb == 2) ? 0 : pb + 1;
    const float* zrd = zs + (k & 1) * ZBUF;
    float*       zwr = zs + ((k + 1) & 1) * ZBUF;
    const float* xrd = xs + rb * XBUF;
    rb = (rb == 2) ? 0 : rb + 1;
    scan_tile(zrd, cs, zofs, whh, hv, cv);           // trans-heavy, 8 chains/wave
    gemv_tile(xrd, zwr, cg, lt, xoff, zofg, w, zb);  // fma-heavy, fills trans stalls
    asm volatile("s_waitcnt lgkmcnt(0)" ::: "memory");
  }
  scan_tile(zs + ZBUF, cs, zofs, whh, hv, cv);       // tile 31 ((31&1)==1)
  asm volatile("s_waitcnt vmcnt(0)" ::: "memory");   // drain tail DMA before LDS dealloc

  // ---- head: out = sigmoid(W_out . [h1,h2] + b_out) ----
  // recurrence (c, half) lives in lanes with (lane&7) == half*4 + c
  const float h1 = __shfl(hv, (lane & 3), 64);
  const float h2 = __shfl(hv, (lane & 3) + 4, 64);
  if (lane < 4) {
    out[b0 + lane] = sigm(fmaf(Wout[0], h1, fmaf(Wout[1], h2, bout[0])));
  }
}

extern "C" void kernel_launch(void* const* d_in, const int* in_sizes, int n_in,
                              void* d_out, int out_size, void* d_ws, size_t ws_size,
                              hipStream_t stream) {
  const float* x    = (const float*)d_in[0];
  const float* Wih1 = (const float*)d_in[1];
  const float* Whh1 = (const float*)d_in[2];
  const float* b1   = (const float*)d_in[3];
  const float* Wih2 = (const float*)d_in[4];
  const float* Whh2 = (const float*)d_in[5];
  const float* b2   = (const float*)d_in[6];
  const float* Wout = (const float*)d_in[7];
  const float* bout = (const float*)d_in[8];
  float* out = (float*)d_out;

  const int B = in_sizes[0] / (T_STEPS * F_IN);      // 4096
  dim3 grid(B / CH), block(64);                      // 1024 blocks -> 4/CU, 1 wave/SIMD
  hipLaunchKernelGGL(lstm2_fused, grid, block, 0, stream,
                     x, Wih1, Whh1, b1, Wih2, Whh2, b2, Wout, bout, out);
}

// Round 3
// 304.740 us; speedup vs baseline: 1.0168x; 1.0079x over previous
//
#include <hip/hip_runtime.h>
#include <stdint.h>

// Fused 2x tiny-LSTM (H=1) over T=512, B=4096, F=25 (12+13 split) + sigmoid head.
// v4: producer-consumer wave specialization. Evidence from v1-v3 (all ~60us):
// the 512-step serial scan costs ~21-25us of per-WAVE issue+latency, and every
// version paid it on every SIMD. v4 pays it on ONE wave per block:
//   wave 0,1: stage x (global_load_lds, counted vmcnt) + GEMV z for 8 own chains
//   wave 2:   scan 32 recurrences (16 chains x 2 LSTMs), exactly 1 per lane,
//             zero redundancy, from a transposed z[t][rec][4] LDS layout.
// Raw s_barrier per tile (no vmcnt drain); producers publish z with lgkmcnt(0).
// Chip pace = max(HBM 33us, scan-wave ~20us, GEMV ~8us) ~= 38us.

#define T_STEPS 512
#define F_IN    25
#define TC      16
#define NTILES  (T_STEPS / TC)     // 32
#define CH      16                 // chains per block
#define CPW     8                  // chains per producer wave
#define XROW    520                // floats per chain per x tile (400 data + 112 clamp spill)
#define XBUF    (CH * XROW)        // 8320 floats per x buffer
#define ZROWP   132                // floats per timestep row: 32 recs * 4 + 4 pad
#define ZBUF    (TC * ZROWP)       // 2112 floats per z buffer
#define LOG2E   1.44269504088896340736f

typedef const __attribute__((address_space(1))) void* as1_cvp;
typedef __attribute__((address_space(3)))       void* as3_vp;

__device__ __forceinline__ void gll16(const float* gsrc, const float* ldst) {
  // async global->LDS, 16 B/lane. LDS dst must be wave-uniform; HW adds lane*16.
  __builtin_amdgcn_global_load_lds((as1_cvp)(uintptr_t)gsrc,
                                   (as3_vp)(uint32_t)(uintptr_t)ldst, 16, 0, 0);
}

__device__ __forceinline__ float sigm(float v) {
  return __builtin_amdgcn_rcpf(1.0f + __builtin_amdgcn_exp2f(v * (-LOG2E)));
}
__device__ __forceinline__ float tanh_(float v) {
  // tanh(x) = 2*sigmoid(2x) - 1
  return fmaf(2.0f, __builtin_amdgcn_rcpf(1.0f + __builtin_amdgcn_exp2f(v * (-2.0f * LOG2E))), -1.0f);
}

__device__ __forceinline__ void prefetch_tile(const float* __restrict__ x, int b0, int wid,
                                              int tile, float* xbuf, int lane) {
  // this wave stages its own 8 chains: 400 contiguous floats each -> 2 gll16/chain
  const float* base = x + (size_t)(b0 + wid * CPW) * (T_STEPS * F_IN) + tile * (TC * F_IN);
  float* l0 = xbuf + (wid * CPW) * XROW;
  const int i1 = lane * 4;          // floats 0..255
  int i2 = 256 + lane * 4;          // floats 256..399 (clamped lanes fill XROW pad)
  if (i2 > 396) i2 = 396;
#pragma unroll
  for (int cc = 0; cc < CPW; ++cc) {
    const float* g0 = base + cc * (T_STEPS * F_IN);
    gll16(g0 + i1, l0 + cc * XROW);          // uniform LDS base per inst
    gll16(g0 + i2, l0 + cc * XROW + 256);    // dst floats 256..511 < 520, safe
  }
}

__device__ __forceinline__ void gemv_tile(const float* __restrict__ xbuf, float* __restrict__ zwr,
                                          int lane, int wid,
                                          const float* __restrict__ w, const float* __restrict__ zb) {
  // producer mapping: lane -> (t, half) fixed; p -> chain. 4 tasks/lane.
  const int t    = lane & 15;
  const int h    = (lane >> 4) & 1;        // 0 -> LSTM1 (w zero-padded), 1 -> LSTM2
  const int chl  = lane >> 5;              // 0..1
  const int xoff = h * 12;
#pragma unroll
  for (int p = 0; p < 4; ++p) {
    const int cg = wid * CPW + p * 2 + chl;          // chain within block
    const float* xr = xbuf + cg * XROW + t * F_IN + xoff;
    float z0 = zb[0], z1 = zb[1], z2 = zb[2], z3 = zb[3];
#pragma unroll
    for (int f = 0; f < 13; ++f) {
      const float xv = xr[f];
      z0 = fmaf(w[0 * 13 + f], xv, z0);
      z1 = fmaf(w[1 * 13 + f], xv, z1);
      z2 = fmaf(w[2 * 13 + f], xv, z2);
      z3 = fmaf(w[3 * 13 + f], xv, z3);
    }
    const int rec = 2 * cg + h;                       // transposed layout z[t][rec][4]
    *(float4*)(zwr + t * ZROWP + rec * 4) = make_float4(z0, z1, z2, z3);
  }
}

__device__ __forceinline__ void scan_tile(const float* __restrict__ zrd, int rec,
                                          const float* __restrict__ whh, float& hv, float& cv) {
  // consumer mapping: 1 recurrence per lane (lanes 32..63 duplicate -> broadcast reads)
#pragma unroll
  for (int t = 0; t < TC; ++t) {
    const float4 z4 = *(const float4*)(zrd + t * ZROWP + rec * 4);
    const float pi = fmaf(hv, whh[0], z4.x);
    const float pf = fmaf(hv, whh[1], z4.y);
    const float pg = fmaf(hv, whh[2], z4.z);
    const float po = fmaf(hv, whh[3], z4.w);
    const float ai = sigm(pi);
    const float af = sigm(pf);
    const float ag = tanh_(pg);
    const float ao = sigm(po);
    cv = fmaf(af, cv, ai * ag);
    hv = ao * tanh_(cv);
  }
}

__global__ void __launch_bounds__(192, 1)
lstm2_fused(const float* __restrict__ x,
            const float* __restrict__ Wih1, const float* __restrict__ Whh1, const float* __restrict__ b1,
            const float* __restrict__ Wih2, const float* __restrict__ Whh2, const float* __restrict__ b2,
            const float* __restrict__ Wout, const float* __restrict__ bout,
            float* __restrict__ out)
{
  __shared__ __align__(16) float xs[3 * XBUF];   // 99840 B: triple-buffered x tiles
  __shared__ __align__(16) float zs[2 * ZBUF];   // 16896 B: double-buffered z, [t][rec][4]

  const int lane = threadIdx.x & 63;
  const int wid  = threadIdx.x >> 6;   // 0,1: producers; 2: scan
  const int b0   = blockIdx.x * CH;

  // producer weights (selected by gemv half), scan weights (selected by rec&1)
  const int hg = (lane >> 4) & 1;
  const int hs = lane & 1;
  float w[52], zb[4], whh[4];
#pragma unroll
  for (int j = 0; j < 4; ++j) {
#pragma unroll
    for (int f = 0; f < 13; ++f) {
      const float wa = (f < 12) ? Wih1[j * 12 + f] : 0.0f;
      const float wb = Wih2[j * 13 + f];
      w[j * 13 + f] = hg ? wb : wa;
    }
    zb[j]  = hg ? b2[j]   : b1[j];
    whh[j] = hs ? Whh2[j] : Whh1[j];
  }

  float hv = 0.0f, cv = 0.0f;
  const int rec = lane & 31;           // scan recurrence id: chain = rec>>1, half = rec&1

  // ---- prologue: producers stage tiles 0,1,2 and compute z[0] ----
  if (wid < 2) {
    prefetch_tile(x, b0, wid, 0, xs + 0 * XBUF, lane);
    prefetch_tile(x, b0, wid, 1, xs + 1 * XBUF, lane);
    prefetch_tile(x, b0, wid, 2, xs + 2 * XBUF, lane);
    asm volatile("s_waitcnt vmcnt(32)" ::: "memory");   // tile 0 staged; 1,2 in flight
    gemv_tile(xs, zs, lane, wid, w, zb);
    asm volatile("s_waitcnt lgkmcnt(0)" ::: "memory");  // publish z[0]
  }
  __builtin_amdgcn_s_barrier();

  // ---- steady state: scan(k) on wave 2 || gemv(k+1)+prefetch(k+3) on waves 0,1 ----
  for (int k = 0; k < NTILES - 1; ++k) {
    if (wid < 2) {
      if (k < NTILES - 3) {
        asm volatile("s_waitcnt vmcnt(16)" ::: "memory");  // x[k+1] staged, x[k+2] in flight
        prefetch_tile(x, b0, wid, k + 3, xs + (k % 3) * XBUF, lane);
      } else {
        asm volatile("s_waitcnt vmcnt(0)" ::: "memory");   // tail: drain remaining tiles
      }
      gemv_tile(xs + ((k + 1) % 3) * XBUF, zs + ((k + 1) & 1) * ZBUF, lane, wid, w, zb);
      asm volatile("s_waitcnt lgkmcnt(0)" ::: "memory");   // publish z[k+1]
    } else {
      scan_tile(zs + (k & 1) * ZBUF, rec, whh, hv, cv);
    }
    __builtin_amdgcn_s_barrier();
  }

  // ---- tail: scan tile 31 (parity 1), then head on the scan wave ----
  if (wid == 2) {
    scan_tile(zs + ZBUF, rec, whh, hv, cv);
    const float h1 = __shfl(hv, (lane & 30), 64);          // rec 2c   (LSTM1)
    const float h2 = __shfl(hv, (lane & 30) | 1, 64);      // rec 2c+1 (LSTM2)
    if (lane < 32 && (lane & 1) == 0) {
      out[b0 + (lane >> 1)] = sigm(fmaf(Wout[0], h1, fmaf(Wout[1], h2, bout[0])));
    }
  }
}

extern "C" void kernel_launch(void* const* d_in, const int* in_sizes, int n_in,
                              void* d_out, int out_size, void* d_ws, size_t ws_size,
                              hipStream_t stream) {
  const float* x    = (const float*)d_in[0];
  const float* Wih1 = (const float*)d_in[1];
  const float* Whh1 = (const float*)d_in[2];
  const float* b1   = (const float*)d_in[3];
  const float* Wih2 = (const float*)d_in[4];
  const float* Whh2 = (const float*)d_in[5];
  const float* b2   = (const float*)d_in[6];
  const float* Wout = (const float*)d_in[7];
  const float* bout = (const float*)d_in[8];
  float* out = (float*)d_out;

  const int B = in_sizes[0] / (T_STEPS * F_IN);      // 4096
  dim3 grid(B / CH), block(192);                     // 256 blocks -> 1 block/CU
  hipLaunchKernelGGL(lstm2_fused, grid, block, 0, stream,
                     x, Wih1, Whh1, b1, Wih2, Whh2, b2, Wout, bout, out);
}